// Round 10
// baseline (333.886 us; speedup 1.0000x reference)
//
#include <hip/hip_runtime.h>

using uint = unsigned int;
using ushort = unsigned short;

typedef __attribute__((ext_vector_type(8))) short bf16x8;
typedef __attribute__((ext_vector_type(4))) float f32x4;

#define ADMM_ITERS 100
#define RHO_C 1.0f
#define SIGMA_C 1e-6f

__device__ inline ushort f2bf(float f) {
  union { float f; uint u; } c; c.f = f;
  uint u = c.u;
  uint r = (u + 0x7fffu + ((u >> 16) & 1u)) >> 16;
  return (ushort)r;
}

// DPP cross-lane moves (VALU pipe, no LDS):
//   0xB1 quad_perm [1,0,3,2]  -> lane ^ 1
//   0x4E quad_perm [2,3,0,1]  -> lane ^ 2
//   0x1B quad_perm [3,2,1,0]  -> lane ^ 3
//   0x141 row_half_mirror     -> lane ^ 7 within 8-lane half-rows
template<int CTRL> __device__ inline float movd(float x) {
  return __int_as_float(__builtin_amdgcn_mov_dpp(__float_as_int(x), CTRL, 0xf, 0xf, true));
}
#define DXOR1(x) movd<0xB1>(x)
#define DXOR2(x) movd<0x4E>(x)
#define HMIR(x)  movd<0x141>(x)   // lane ^ 7 (8-aligned groups)

__device__ inline void gload_lds16(const void* g, void* l) {
  __builtin_amdgcn_global_load_lds(
      (const __attribute__((address_space(1))) void*)g,
      (__attribute__((address_space(3))) void*)l, 16, 0, 0);
}

// ---------------------------------------------------------------------------
// f32 -> bf16 elementwise convert (4 elems/thread, float4 loads)
// ---------------------------------------------------------------------------
__global__ void convert_bf16(const float* __restrict__ in, ushort* __restrict__ out, int n4) {
  int i = blockIdx.x * blockDim.x + threadIdx.x;
  if (i >= n4) return;
  float4 v = ((const float4*)in)[i];
  uint2 p;
  p.x = (uint)f2bf(v.x) | ((uint)f2bf(v.y) << 16);
  p.y = (uint)f2bf(v.z) | ((uint)f2bf(v.w) << 16);
  ((uint2*)out)[i] = p;
}

// ---------------------------------------------------------------------------
// f32 transpose -> bf16: out[c][r] = bf16(in[r][c]); rows c in [C,Cout) zeroed.
// ---------------------------------------------------------------------------
__global__ void transpose_f32_bf16(const float* __restrict__ in, ushort* __restrict__ out,
                                   int R, int C, int Cout) {
  __shared__ float t[32][33];
  const int c0 = blockIdx.x * 32, r0 = blockIdx.y * 32;
  const int tx = threadIdx.x & 31, ty = threadIdx.x >> 5;
  for (int rr = ty; rr < 32; rr += 8) {
    int r = r0 + rr, c = c0 + tx;
    float v = 0.0f;
    if (r < R && c < C) v = in[(long)r * C + c];
    t[rr][tx] = v;
  }
  __syncthreads();
  for (int rr = ty; rr < 32; rr += 8) {
    int c = c0 + rr, r = r0 + tx;
    if (c < Cout && r < R) out[(long)c * R + r] = f2bf(t[tx][rr]);
  }
}

// ---------------------------------------------------------------------------
// ADMM constants. cbuf layout (f32), total 1224:
//   Minv[24x24] @0 | A12[12x24] @576 | G = Minv*A12^T [24x12] @864 |
//   lc[12] @1152 | uc[12] @1164 | lb[24] @1176 | ub[24] @1200
// ---------------------------------------------------------------------------
__global__ void setup_admm(const float* __restrict__ Aeq, const float* __restrict__ beq,
                           const float* __restrict__ A, const float* __restrict__ b,
                           const float* __restrict__ ub, const float* __restrict__ lb,
                           float* __restrict__ cbuf) {
  __shared__ float Aug[24][48];
  __shared__ float A12[12 * 24];
  __shared__ float fac[24];
  const int t = threadIdx.x;
  if (t < 96)  A12[t] = Aeq[t];          // rows 0-3
  if (t < 192) A12[96 + t] = A[t];       // rows 4-11
  __syncthreads();
  for (int idx = t; idx < 576; idx += 256) {
    int j = idx / 24, k = idx % 24;
    float s = (j == k) ? (1.0f + SIGMA_C + 2.0f * RHO_C) : 0.0f;
    for (int r = 0; r < 12; ++r) s += RHO_C * A12[r * 24 + j] * A12[r * 24 + k];
    Aug[j][k] = s;
    Aug[j][24 + k] = (j == k) ? 1.0f : 0.0f;
  }
  __syncthreads();
  for (int p = 0; p < 24; ++p) {
    float rp = 1.0f / Aug[p][p];
    if (t < 24) fac[t] = Aug[t][p];
    __syncthreads();
    if (t < 48) Aug[p][t] *= rp;
    __syncthreads();
    for (int idx = t; idx < 24 * 48; idx += 256) {
      int r = idx / 48, c = idx % 48;
      if (r != p) Aug[r][c] -= fac[r] * Aug[p][c];
    }
    __syncthreads();
  }
  for (int idx = t; idx < 576; idx += 256) cbuf[idx] = Aug[idx / 24][24 + idx % 24];
  for (int idx = t; idx < 288; idx += 256) cbuf[576 + idx] = A12[idx];
  for (int idx = t; idx < 288; idx += 256) {
    int j = idx / 12, r = idx % 12;
    float s = 0.0f;
    for (int k = 0; k < 24; ++k) s += Aug[j][24 + k] * A12[r * 24 + k];
    cbuf[864 + idx] = s;
  }
  if (t < 12) {
    float lv, uv;
    if (t < 4) { lv = beq[t]; uv = lv; }
    else       { lv = -INFINITY; uv = b[t - 4]; }
    cbuf[1152 + t] = lv;
    cbuf[1164 + t] = uv;
  }
  if (t < 24) {
    cbuf[1176 + t] = lb[t];
    cbuf[1200 + t] = ub[t];
  }
}

// ---------------------------------------------------------------------------
// bf16 GEMM, C = A[M,K] * Bt[N,K]^T — m97-style staging (round-8 verified).
// ---------------------------------------------------------------------------
template<int BM, int BN, int WM, int WN, int TM, int TN, int MODE>
__global__ __launch_bounds__(256) void gemm_bt(
    const ushort* __restrict__ A, const ushort* __restrict__ Bt,
    const float* __restrict__ bias, void* __restrict__ Cout_,
    int K, int ldc, int nvalid) {
  __shared__ char lds[(BM + BN) * 64];
  char* ldsA = lds;
  char* ldsB = lds + BM * 64;

  const int tid = threadIdx.x;
  const int wave = tid >> 6;
  const int lane = tid & 63;
  const int blockM = blockIdx.y * BM;
  const int blockN = blockIdx.x * BN;
  const int wm = (wave / WN) * (TM * 16);
  const int wn = (wave % WN) * (TN * 16);

  f32x4 acc[TM][TN] = {};

  const int l15 = lane & 15;
  const int kq = lane >> 4;
  constexpr int AI = BM / 16;
  constexpr int TOT = (BM + BN) / 16;
  const int srow = lane >> 2;
  const int kb = (lane & 3) ^ ((srow >> 1) & 3);

  for (int k0 = 0; k0 < K; k0 += 32) {
    for (int inst = wave; inst < TOT; inst += 4) {
      const bool isA = inst < AI;
      const int i = isA ? inst : inst - AI;
      const ushort* gp = (isA ? A : Bt)
          + (long)((isA ? blockM : blockN) + i * 16 + srow) * K + (k0 + kb * 8);
      char* lp = (isA ? ldsA : ldsB) + i * 1024;
      gload_lds16(gp, lp);
    }
    __syncthreads();

    bf16x8 af[TM], bfr[TN];
#pragma unroll
    for (int i = 0; i < TM; ++i) {
      int r = wm + i * 16 + l15;
      int ch = kq ^ ((r >> 1) & 3);
      af[i] = *(const bf16x8*)(ldsA + r * 64 + ch * 16);
    }
#pragma unroll
    for (int j = 0; j < TN; ++j) {
      int r = wn + j * 16 + l15;
      int ch = kq ^ ((r >> 1) & 3);
      bfr[j] = *(const bf16x8*)(ldsB + r * 64 + ch * 16);
    }
#pragma unroll
    for (int i = 0; i < TM; ++i)
#pragma unroll
      for (int j = 0; j < TN; ++j)
        acc[i][j] = __builtin_amdgcn_mfma_f32_16x16x32_bf16(af[i], bfr[j], acc[i][j], 0, 0, 0);
    __syncthreads();
  }

  const int ro = lane >> 4;
#pragma unroll
  for (int i = 0; i < TM; ++i) {
#pragma unroll
    for (int j = 0; j < TN; ++j) {
      const int col = blockN + wn + j * 16 + l15;
      float bv;
      if (MODE == 0) bv = bias[col];
      else bv = (col < nvalid) ? bias[col] : 0.0f;
#pragma unroll
      for (int r = 0; r < 4; ++r) {
        const int row = blockM + wm + i * 16 + ro * 4 + r;
        float v = acc[i][j][r] + bv;
        if (MODE == 0) {
          v = fmaxf(v, 0.0f);
          ((ushort*)Cout_)[(long)row * ldc + col] = f2bf(v);
        } else {
          if (col < nvalid) ((float*)Cout_)[(long)row * ldc + col] = v;
        }
      }
    }
  }
}

// ---------------------------------------------------------------------------
// ADMM, EIGHT lanes per batch row. Round-9 diagnosis: VALUBusy 68% at 2330
// cyc/iter vs ~760 cyc hand-count -> ~2x instruction bloat from the allocator
// shuffling 306 constants through the unified VGPR/AGPR file (arch alloc
// stuck ~200). Fix: halve the per-lane footprint so it FITS one wave's
// budget. Lane h=lane&7 owns 3 x-indices (j=3h..3h+2) and, duplicated
// across half-groups, 3 constraint rows (r=3(h&3)..+2).
//   - consts/lane: cM 72 + cA 72 + cG 36 + bounds 12 = 192; peak live ~250
//   - __launch_bounds__(256,2): cap 256 VGPR/wave, 2 waves/SIMD (2048 waves)
//   - 24-wide all-gather in 21 DPP movs: quad xors for lanes h^{1,2,3},
//     row_half_mirror (lane^7) + quad xors for h^{7,6,5,4}
//   - w-formulation, iteration-1 peel, I/-I mirror (as verified r6-r9)
// ---------------------------------------------------------------------------
__global__ __launch_bounds__(256, 2) void admm_kernel(
    const float* raw, const float* __restrict__ cbuf, float* outp) {
  const int tid = threadIdx.x;
  const int lane = tid & 63;
  const int h = lane & 7;
  const int hq = h & 3;
  const int row = blockIdx.x * 32 + (tid >> 3);

  // ---- constants, permutation baked into load addresses -------------------
  float cM[3][8][3];   // Minv[3h+jj][3(h^m)+t]
  float cA[3][8][3];   // A12[3(h&3)+tt][3(h^m)+t]
  float cG[3][4][3];   // G[3h+jj][3((h&3)^m)+t]
#pragma unroll
  for (int jj = 0; jj < 3; ++jj)
#pragma unroll
    for (int m = 0; m < 8; ++m) {
      const float* p = cbuf + (3 * h + jj) * 24 + 3 * (h ^ m);
#pragma unroll
      for (int t = 0; t < 3; ++t) cM[jj][m][t] = p[t];
    }
#pragma unroll
  for (int tt = 0; tt < 3; ++tt)
#pragma unroll
    for (int m = 0; m < 8; ++m) {
      const float* p = cbuf + 576 + (3 * hq + tt) * 24 + 3 * (h ^ m);
#pragma unroll
      for (int t = 0; t < 3; ++t) cA[tt][m][t] = p[t];
    }
#pragma unroll
  for (int jj = 0; jj < 3; ++jj)
#pragma unroll
    for (int m = 0; m < 4; ++m) {
      const float* p = cbuf + 864 + (3 * h + jj) * 12 + 3 * (hq ^ m);
#pragma unroll
      for (int t = 0; t < 3; ++t) cG[jj][m][t] = p[t];
    }
  float lbv[3], ubv[3], lcb[3], ucb[3];
#pragma unroll
  for (int jj = 0; jj < 3; ++jj) {
    lbv[jj] = cbuf[1176 + 3 * h + jj];
    ubv[jj] = cbuf[1200 + 3 * h + jj];
  }
#pragma unroll
  for (int tt = 0; tt < 3; ++tt) {
    lcb[tt] = cbuf[1152 + 3 * hq + tt];
    ucb[tt] = cbuf[1164 + 3 * hq + tt];
  }

  // ---- q slice ------------------------------------------------------------
  float qv[3];
  {
    const float* rp = raw + (long)row * 24 + 3 * h;
#pragma unroll
    for (int i = 0; i < 3; ++i) qv[i] = rp[i];
  }

  // 24-wide all-gather: g[m][t] = src[t] of lane h^m. 21 DPP movs.
#define GATHER24(g, s0, s1, s2)                                   \
  { g[0][0]=s0; g[0][1]=s1; g[0][2]=s2;                           \
    for (int t = 0; t < 3; ++t) g[1][t] = DXOR1(g[0][t]);         \
    for (int t = 0; t < 3; ++t) g[2][t] = DXOR2(g[0][t]);         \
    for (int t = 0; t < 3; ++t) g[3][t] = DXOR2(g[1][t]);         \
    for (int t = 0; t < 3; ++t) g[7][t] = HMIR(g[0][t]);          \
    for (int t = 0; t < 3; ++t) g[6][t] = DXOR1(g[7][t]);         \
    for (int t = 0; t < 3; ++t) g[5][t] = DXOR2(g[7][t]);         \
    for (int t = 0; t < 3; ++t) g[4][t] = DXOR2(g[6][t]); }

  // ---- iteration-1 peel: X1 = Minv*raw, wb=X1(owned), wc = A12*X1 ---------
  float ga[8][3];
  GATHER24(ga, qv[0], qv[1], qv[2]);
  float qM[3], X[3], wb[3], wc[3];
#pragma unroll
  for (int jj = 0; jj < 3; ++jj) {
    float s = 0.0f;
#pragma unroll
    for (int m = 0; m < 8; ++m)
#pragma unroll
      for (int t = 0; t < 3; ++t) s += cM[jj][m][t] * ga[m][t];
    qM[jj] = s; X[jj] = s; wb[jj] = s;
  }
  GATHER24(ga, X[0], X[1], X[2]);
#pragma unroll
  for (int tt = 0; tt < 3; ++tt) {
    float s = 0.0f;
#pragma unroll
    for (int m = 0; m < 8; ++m)
#pragma unroll
      for (int t = 0; t < 3; ++t) s += cA[tt][m][t] * ga[m][t];
    wc[tt] = s;
  }

  // ---- 99 iterations: pure VALU + DPP -------------------------------------
#pragma unroll 1
  for (int it = 1; it < ADMM_ITERS; ++it) {
    float Zb[3], Zc[3], ub2[3], ucv[3];
#pragma unroll
    for (int jj = 0; jj < 3; ++jj) {
      Zb[jj] = fminf(fmaxf(wb[jj], lbv[jj]), ubv[jj]);
      ub2[jj] = 2.0f * (2.0f * Zb[jj] - wb[jj]);          // 2*u_b (mirror x2)
    }
#pragma unroll
    for (int tt = 0; tt < 3; ++tt) {
      Zc[tt] = fminf(fmaxf(wc[tt], lcb[tt]), ucb[tt]);
      ucv[tt] = 2.0f * Zc[tt] - wc[tt];                   // u_c
    }
    GATHER24(ga, ub2[0], ub2[1], ub2[2]);
    float uca[4][3];
#pragma unroll
    for (int t = 0; t < 3; ++t) uca[0][t] = ucv[t];
#pragma unroll
    for (int t = 0; t < 3; ++t) uca[1][t] = DXOR1(uca[0][t]);
#pragma unroll
    for (int t = 0; t < 3; ++t) uca[2][t] = DXOR2(uca[0][t]);
#pragma unroll
    for (int t = 0; t < 3; ++t) uca[3][t] = DXOR2(uca[1][t]);

    // X = qM + Minv*(2u_b) + G*u_c
#pragma unroll
    for (int jj = 0; jj < 3; ++jj) {
      float s = qM[jj];
#pragma unroll
      for (int m = 0; m < 8; ++m)
#pragma unroll
        for (int t = 0; t < 3; ++t) s += cM[jj][m][t] * ga[m][t];
#pragma unroll
      for (int m = 0; m < 4; ++m)
#pragma unroll
        for (int t = 0; t < 3; ++t) s += cG[jj][m][t] * uca[m][t];
      X[jj] = s;
      wb[jj] = s + (wb[jj] - Zb[jj]);                     // w_b' = X + Y_b
    }
    // w_c' = A12*X + (w_c - Z_c)
    GATHER24(ga, X[0], X[1], X[2]);
#pragma unroll
    for (int tt = 0; tt < 3; ++tt) {
      float s = wc[tt] - Zc[tt];
#pragma unroll
      for (int m = 0; m < 8; ++m)
#pragma unroll
        for (int t = 0; t < 3; ++t) s += cA[tt][m][t] * ga[m][t];
      wc[tt] = s;
    }
  }

  float* op = outp + (long)row * 24 + 3 * h;
#pragma unroll
  for (int i = 0; i < 3; ++i) op[i] = X[i];
}

// ---------------------------------------------------------------------------
extern "C" void kernel_launch(void* const* d_in, const int* in_sizes, int n_in,
                              void* d_out, int out_size, void* d_ws, size_t ws_size,
                              hipStream_t stream) {
  const float* state = (const float*)d_in[0];
  const float* Aeq   = (const float*)d_in[1];
  const float* beq   = (const float*)d_in[2];
  const float* Ain   = (const float*)d_in[3];
  const float* bin   = (const float*)d_in[4];
  const float* ub    = (const float*)d_in[5];
  const float* lb    = (const float*)d_in[6];
  const float* W1    = (const float*)d_in[7];
  const float* b1    = (const float*)d_in[8];
  const float* W2    = (const float*)d_in[9];
  const float* b2    = (const float*)d_in[10];
  const float* W3    = (const float*)d_in[11];
  const float* b3    = (const float*)d_in[12];

  const int Bn = in_sizes[0] / 512;            // 16384
  char* ws = (char*)d_ws;
  ushort* stateB = (ushort*)(ws + 0);          // 16384x512 bf16  (16 MB)
  ushort* W1T    = (ushort*)(ws + 16777216);   // 1024x512        (1 MB)
  ushort* W2T    = (ushort*)(ws + 17825792);   // 1024x1024       (2 MB)
  ushort* W3T    = (ushort*)(ws + 19922944);   // 32x1024 (rows>=24 zero)
  float*  cbuf   = (float*) (ws + 19988480);   // 1224 f32
  ushort* H1     = (ushort*)(ws + 21565440);   // 16384x1024 bf16 (32 MB)
  ushort* H2     = (ushort*)(ws + 55119872);   // 16384x1024 bf16 (32 MB)
  float*  rawb   = (float*)d_out;              // gemm3 out = admm in (in-place)

  const int n4 = (Bn * 512) / 4;
  convert_bf16<<<(n4 + 255) / 256, 256, 0, stream>>>(state, stateB, n4);
  transpose_f32_bf16<<<dim3(32, 16), 256, 0, stream>>>(W1, W1T, 512, 1024, 1024);
  transpose_f32_bf16<<<dim3(32, 32), 256, 0, stream>>>(W2, W2T, 1024, 1024, 1024);
  transpose_f32_bf16<<<dim3(1, 32),  256, 0, stream>>>(W3, W3T, 1024, 24, 32);
  setup_admm<<<1, 256, 0, stream>>>(Aeq, beq, Ain, bin, ub, lb, cbuf);

  gemm_bt<128, 128, 2, 2, 4, 4, 0><<<dim3(8, Bn / 128), 256, 0, stream>>>(
      stateB, W1T, b1, H1, 512, 1024, 1024);
  gemm_bt<128, 128, 2, 2, 4, 4, 0><<<dim3(8, Bn / 128), 256, 0, stream>>>(
      H1, W2T, b2, H2, 1024, 1024, 1024);
  gemm_bt<64, 32, 4, 1, 1, 2, 1><<<dim3(1, Bn / 64), 256, 0, stream>>>(
      H2, W3T, b3, rawb, 1024, 24, 24);

  admm_kernel<<<Bn / 32, 256, 0, stream>>>(rawb, cbuf, (float*)d_out);
}

// Round 11
// 295.558 us; speedup vs baseline: 1.1297x; 1.1297x over previous
//
#include <hip/hip_runtime.h>

using uint = unsigned int;
using ushort = unsigned short;

typedef __attribute__((ext_vector_type(8))) short bf16x8;
typedef __attribute__((ext_vector_type(4))) float f32x4;

#define ADMM_ITERS 100
#define RHO_C 1.0f
#define SIGMA_C 1e-6f

__device__ inline ushort f2bf(float f) {
  union { float f; uint u; } c; c.f = f;
  uint u = c.u;
  uint r = (u + 0x7fffu + ((u >> 16) & 1u)) >> 16;
  return (ushort)r;
}

__device__ inline void gload_lds16(const void* g, void* l) {
  __builtin_amdgcn_global_load_lds(
      (const __attribute__((address_space(1))) void*)g,
      (__attribute__((address_space(3))) void*)l, 16, 0, 0);
}

// Split 8 f32 -> hi/lo bf16x8 by TRUNCATION (hi = mantissa-masked; lo = exact
// residual, truncated). Residual error ~2^-16 relative.
__device__ inline void splitPack(const float* x, bf16x8& hi, bf16x8& lo) {
#pragma unroll
  for (int j = 0; j < 8; ++j) {
    uint b = __float_as_uint(x[j]);
    uint hb = b & 0xffff0000u;
    float lf = x[j] - __uint_as_float(hb);
    hi[j] = (short)(b >> 16);
    lo[j] = (short)(__float_as_uint(lf) >> 16);
  }
}

// ---------------------------------------------------------------------------
// f32 -> bf16 elementwise convert
// ---------------------------------------------------------------------------
__global__ void convert_bf16(const float* __restrict__ in, ushort* __restrict__ out, int n4) {
  int i = blockIdx.x * blockDim.x + threadIdx.x;
  if (i >= n4) return;
  float4 v = ((const float4*)in)[i];
  uint2 p;
  p.x = (uint)f2bf(v.x) | ((uint)f2bf(v.y) << 16);
  p.y = (uint)f2bf(v.z) | ((uint)f2bf(v.w) << 16);
  ((uint2*)out)[i] = p;
}

// ---------------------------------------------------------------------------
// f32 transpose -> bf16
// ---------------------------------------------------------------------------
__global__ void transpose_f32_bf16(const float* __restrict__ in, ushort* __restrict__ out,
                                   int R, int C, int Cout) {
  __shared__ float t[32][33];
  const int c0 = blockIdx.x * 32, r0 = blockIdx.y * 32;
  const int tx = threadIdx.x & 31, ty = threadIdx.x >> 5;
  for (int rr = ty; rr < 32; rr += 8) {
    int r = r0 + rr, c = c0 + tx;
    float v = 0.0f;
    if (r < R && c < C) v = in[(long)r * C + c];
    t[rr][tx] = v;
  }
  __syncthreads();
  for (int rr = ty; rr < 32; rr += 8) {
    int c = c0 + rr, r = r0 + tx;
    if (c < Cout && r < R) out[(long)c * R + r] = f2bf(t[tx][rr]);
  }
}

// ---------------------------------------------------------------------------
// ADMM setup -> MFMA operand form.
// W-state iteration (verified r6-r10): u = 2*clip(W)-W,
//   W' = base + T*u + (W - Z),  T = [[2Minv, G],[2*A12*Minv, A12*G]] (36x36)
//   base = T0*q per row,       T0 = [[Minv],[A12*Minv]] (36x24)
// Outputs (B-operand "Bt" layout = row-major [n_out][k_in], bf16 hi+lo,
// rounded split):  Th/Tl [48][64], T0h/T0l [48][32], bounds bl/bu [48].
// ---------------------------------------------------------------------------
__global__ void setup_admm(const float* __restrict__ Aeq, const float* __restrict__ beq,
                           const float* __restrict__ A, const float* __restrict__ b,
                           const float* __restrict__ ub, const float* __restrict__ lb,
                           ushort* __restrict__ Th, ushort* __restrict__ Tl,
                           ushort* __restrict__ T0h, ushort* __restrict__ T0l,
                           float* __restrict__ blp, float* __restrict__ bup) {
  __shared__ float Aug[24][48];
  __shared__ float A12[12 * 24];
  __shared__ float fac[24];
  __shared__ float Tx[24][36];
  const int t = threadIdx.x;
  // zero-init padded operand arrays
  for (int i = t; i < 48 * 64; i += 256) { Th[i] = 0; Tl[i] = 0; }
  for (int i = t; i < 48 * 32; i += 256) { T0h[i] = 0; T0l[i] = 0; }
  if (t < 96)  A12[t] = Aeq[t];
  if (t < 192) A12[96 + t] = A[t];
  __syncthreads();
  for (int idx = t; idx < 576; idx += 256) {
    int j = idx / 24, k = idx % 24;
    float s = (j == k) ? (1.0f + SIGMA_C + 2.0f * RHO_C) : 0.0f;
    for (int r = 0; r < 12; ++r) s += RHO_C * A12[r * 24 + j] * A12[r * 24 + k];
    Aug[j][k] = s;
    Aug[j][24 + k] = (j == k) ? 1.0f : 0.0f;
  }
  __syncthreads();
  for (int p = 0; p < 24; ++p) {
    float rp = 1.0f / Aug[p][p];
    if (t < 24) fac[t] = Aug[t][p];
    __syncthreads();
    if (t < 48) Aug[p][t] *= rp;
    __syncthreads();
    for (int idx = t; idx < 24 * 48; idx += 256) {
      int r = idx / 48, c = idx % 48;
      if (r != p) Aug[r][c] -= fac[r] * Aug[p][c];
    }
    __syncthreads();
  }
  // Minv(n,k) = Aug[n][24+k]
  auto splitStore = [](ushort* hp, ushort* lp, int i, float v) {
    ushort hs = f2bf(v);                               // rounded hi
    float hf = __uint_as_float(((uint)hs) << 16);
    ushort ls = f2bf(v - hf);                          // rounded lo
    hp[i] = hs; lp[i] = ls;
  };
  // T rows 0..23: [2*Minv | G],  G[n][r] = sum_j Minv[n][j]*A12[r][j]
  for (int idx = t; idx < 24 * 36; idx += 256) {
    int n = idx / 36, k = idx % 36;
    float v;
    if (k < 24) v = 2.0f * Aug[n][24 + k];
    else {
      v = 0.0f;
      for (int j = 0; j < 24; ++j) v += Aug[n][24 + j] * A12[(k - 24) * 24 + j];
    }
    Tx[n][k] = v;
    splitStore(Th, Tl, n * 64 + k, v);
  }
  __syncthreads();
  // T rows 24..35: A12 * Tx
  for (int idx = t; idx < 12 * 36; idx += 256) {
    int m = idx / 36, k = idx % 36;
    float v = 0.0f;
    for (int j = 0; j < 24; ++j) v += A12[m * 24 + j] * Tx[j][k];
    splitStore(Th, Tl, (24 + m) * 64 + k, v);
  }
  // T0 rows: n<24 -> Minv[n][k]; n>=24 -> (A12*Minv)[n-24][k]
  for (int idx = t; idx < 36 * 24; idx += 256) {
    int n = idx / 24, k = idx % 24;
    float v;
    if (n < 24) v = Aug[n][24 + k];
    else {
      v = 0.0f;
      for (int j = 0; j < 24; ++j) v += A12[(n - 24) * 24 + j] * Aug[j][24 + k];
    }
    splitStore(T0h, T0l, n * 32 + k, v);
  }
  // bounds per W column
  if (t < 48) {
    float lv, uv;
    if (t < 24)      { lv = lb[t]; uv = ub[t]; }
    else if (t < 28) { lv = beq[t - 24]; uv = lv; }
    else if (t < 36) { lv = -1e30f; uv = b[t - 28]; }
    else             { lv = -1e30f; uv = 1e30f; }
    blp[t] = lv; bup[t] = uv;
  }
}

// ---------------------------------------------------------------------------
// bf16 GEMM, C = A[M,K] * Bt[N,K]^T — m97-style staging (round-8 verified).
// ---------------------------------------------------------------------------
template<int BM, int BN, int WM, int WN, int TM, int TN, int MODE>
__global__ __launch_bounds__(256) void gemm_bt(
    const ushort* __restrict__ A, const ushort* __restrict__ Bt,
    const float* __restrict__ bias, void* __restrict__ Cout_,
    int K, int ldc, int nvalid) {
  __shared__ char lds[(BM + BN) * 64];
  char* ldsA = lds;
  char* ldsB = lds + BM * 64;

  const int tid = threadIdx.x;
  const int wave = tid >> 6;
  const int lane = tid & 63;
  const int blockM = blockIdx.y * BM;
  const int blockN = blockIdx.x * BN;
  const int wm = (wave / WN) * (TM * 16);
  const int wn = (wave % WN) * (TN * 16);

  f32x4 acc[TM][TN] = {};

  const int l15 = lane & 15;
  const int kq = lane >> 4;
  constexpr int AI = BM / 16;
  constexpr int TOT = (BM + BN) / 16;
  const int srow = lane >> 2;
  const int kb = (lane & 3) ^ ((srow >> 1) & 3);

  for (int k0 = 0; k0 < K; k0 += 32) {
    for (int inst = wave; inst < TOT; inst += 4) {
      const bool isA = inst < AI;
      const int i = isA ? inst : inst - AI;
      const ushort* gp = (isA ? A : Bt)
          + (long)((isA ? blockM : blockN) + i * 16 + srow) * K + (k0 + kb * 8);
      char* lp = (isA ? ldsA : ldsB) + i * 1024;
      gload_lds16(gp, lp);
    }
    __syncthreads();

    bf16x8 af[TM], bfr[TN];
#pragma unroll
    for (int i = 0; i < TM; ++i) {
      int r = wm + i * 16 + l15;
      int ch = kq ^ ((r >> 1) & 3);
      af[i] = *(const bf16x8*)(ldsA + r * 64 + ch * 16);
    }
#pragma unroll
    for (int j = 0; j < TN; ++j) {
      int r = wn + j * 16 + l15;
      int ch = kq ^ ((r >> 1) & 3);
      bfr[j] = *(const bf16x8*)(ldsB + r * 64 + ch * 16);
    }
#pragma unroll
    for (int i = 0; i < TM; ++i)
#pragma unroll
      for (int j = 0; j < TN; ++j)
        acc[i][j] = __builtin_amdgcn_mfma_f32_16x16x32_bf16(af[i], bfr[j], acc[i][j], 0, 0, 0);
    __syncthreads();
  }

  const int ro = lane >> 4;
#pragma unroll
  for (int i = 0; i < TM; ++i) {
#pragma unroll
    for (int j = 0; j < TN; ++j) {
      const int col = blockN + wn + j * 16 + l15;
      float bv;
      if (MODE == 0) bv = bias[col];
      else bv = (col < nvalid) ? bias[col] : 0.0f;
#pragma unroll
      for (int r = 0; r < 4; ++r) {
        const int row = blockM + wm + i * 16 + ro * 4 + r;
        float v = acc[i][j][r] + bv;
        if (MODE == 0) {
          v = fmaxf(v, 0.0f);
          ((ushort*)Cout_)[(long)row * ldc + col] = f2bf(v);
        } else {
          if (col < nvalid) ((float*)Cout_)[(long)row * ldc + col] = v;
        }
      }
    }
  }
}

// ---------------------------------------------------------------------------
// ADMM via MFMA. 16 batch rows per wave; W-state kept as 3 C-layout fragments
// (tiles of 16 cols, 48 padded). Per iteration:
//   u = 2*clip(W)-W  (elementwise, C-layout)
//   C->A relayout of u via intra-wave LDS transpose (no barrier needed)
//   W' = [base + (W-Z)] + U*T^T  via 18 MFMAs (hi/lo bf16 split x 2 K-chunks
//        x 3 N-tiles), T fragments register-resident (48 VGPRs TOTAL)
// Round 8-10 post-mortem: per-lane constant arrays >70 regs trigger allocator
// remat (~2x inst bloat, unfixable via launch_bounds/PIN). MFMA form shares
// T across lanes -> footprint ~130 regs incl. state; no remat pressure.
// LDS row stride 68 f32: b128-aligned, balanced banks (8 dw/bank = floor).
// ---------------------------------------------------------------------------
__global__ __launch_bounds__(256) void admm_mfma(
    const float* raw,
    const ushort* __restrict__ Th, const ushort* __restrict__ Tl,
    const ushort* __restrict__ T0h, const ushort* __restrict__ T0l,
    const float* __restrict__ blp, const float* __restrict__ bup,
    float* outp) {
  __shared__ __align__(16) float Ubuf[4][16][68];
  const int tid = threadIdx.x, wave = tid >> 6, lane = tid & 63;
  const int l15 = lane & 15, q = lane >> 4;
  const long rowbase = (long)blockIdx.x * 64 + wave * 16;
  float (*U)[68] = Ubuf[wave];

  // zero K-pad region (cols 48..63) once; never written again
  for (int idx = lane; idx < 256; idx += 64)
    U[idx >> 4][48 + (idx & 15)] = 0.0f;

  float bl[3], bu[3];
#pragma unroll
  for (int t = 0; t < 3; ++t) { bl[t] = blp[16 * t + l15]; bu[t] = bup[16 * t + l15]; }

  // ---- peel: base = W_1 = T0 * q ------------------------------------------
  f32x4 W[3], base[3];
  {
    bf16x8 t0h[3], t0l[3];
#pragma unroll
    for (int t = 0; t < 3; ++t) {
      t0h[t] = *(const bf16x8*)(T0h + (16 * t + l15) * 32 + q * 8);
      t0l[t] = *(const bf16x8*)(T0l + (16 * t + l15) * 32 + q * 8);
    }
    float qa[8];
    if (q < 3) {
      const float* rp = raw + (rowbase + l15) * 24 + q * 8;
      float4 v0 = *(const float4*)rp;
      float4 v1 = *(const float4*)(rp + 4);
      qa[0] = v0.x; qa[1] = v0.y; qa[2] = v0.z; qa[3] = v0.w;
      qa[4] = v1.x; qa[5] = v1.y; qa[6] = v1.z; qa[7] = v1.w;
    } else {
#pragma unroll
      for (int j = 0; j < 8; ++j) qa[j] = 0.0f;
    }
    bf16x8 qhi, qlo;
    splitPack(qa, qhi, qlo);
#pragma unroll
    for (int t = 0; t < 3; ++t) {
      f32x4 acc = {0.0f, 0.0f, 0.0f, 0.0f};
      acc = __builtin_amdgcn_mfma_f32_16x16x32_bf16(qhi, t0h[t], acc, 0, 0, 0);
      acc = __builtin_amdgcn_mfma_f32_16x16x32_bf16(qlo, t0h[t], acc, 0, 0, 0);
      acc = __builtin_amdgcn_mfma_f32_16x16x32_bf16(qhi, t0l[t], acc, 0, 0, 0);
      base[t] = acc; W[t] = acc;
    }
  }

  // ---- T B-fragments (register-resident, shared layout) -------------------
  bf16x8 tbh[2][3], tbl[2][3];
#pragma unroll
  for (int c = 0; c < 2; ++c)
#pragma unroll
    for (int t = 0; t < 3; ++t) {
      tbh[c][t] = *(const bf16x8*)(Th + (16 * t + l15) * 64 + 32 * c + q * 8);
      tbl[c][t] = *(const bf16x8*)(Tl + (16 * t + l15) * 64 + 32 * c + q * 8);
    }

  float yb0[4], yb1[4];
#pragma unroll 1
  for (int it = 1; it < ADMM_ITERS; ++it) {
    f32x4 C[3];
#pragma unroll
    for (int t = 0; t < 3; ++t) {
#pragma unroll
      for (int r = 0; r < 4; ++r) {
        float w = W[t][r];
        float z = fminf(fmaxf(w, bl[t]), bu[t]);
        float u = 2.0f * z - w;
        float y = w - z;
        C[t][r] = base[t][r] + y;
        if (t == 0) yb0[r] = y;
        if (t == 1) yb1[r] = y;
        U[q * 4 + r][16 * t + l15] = u;
      }
    }
    bf16x8 uh[2], ul[2];
#pragma unroll
    for (int c = 0; c < 2; ++c) {
      const float* up = &U[l15][32 * c + q * 8];
      float4 a0 = *(const float4*)up;
      float4 a1 = *(const float4*)(up + 4);
      float ua[8] = {a0.x, a0.y, a0.z, a0.w, a1.x, a1.y, a1.z, a1.w};
      splitPack(ua, uh[c], ul[c]);
    }
#pragma unroll
    for (int t = 0; t < 3; ++t) {
      f32x4 acc = C[t];
#pragma unroll
      for (int c = 0; c < 2; ++c) {
        acc = __builtin_amdgcn_mfma_f32_16x16x32_bf16(uh[c], tbh[c][t], acc, 0, 0, 0);
        acc = __builtin_amdgcn_mfma_f32_16x16x32_bf16(ul[c], tbh[c][t], acc, 0, 0, 0);
        acc = __builtin_amdgcn_mfma_f32_16x16x32_bf16(uh[c], tbl[c][t], acc, 0, 0, 0);
      }
      W[t] = acc;
    }
  }

  // X_100 = W_100,b - (W_99 - Z_99)_b ; store cols 0..23
#pragma unroll
  for (int r = 0; r < 4; ++r) {
    const long row = rowbase + q * 4 + r;
    outp[row * 24 + l15] = W[0][r] - yb0[r];
    if (l15 < 8) outp[row * 24 + 16 + l15] = W[1][r] - yb1[r];
  }
}

// ---------------------------------------------------------------------------
extern "C" void kernel_launch(void* const* d_in, const int* in_sizes, int n_in,
                              void* d_out, int out_size, void* d_ws, size_t ws_size,
                              hipStream_t stream) {
  const float* state = (const float*)d_in[0];
  const float* Aeq   = (const float*)d_in[1];
  const float* beq   = (const float*)d_in[2];
  const float* Ain   = (const float*)d_in[3];
  const float* bin   = (const float*)d_in[4];
  const float* ub    = (const float*)d_in[5];
  const float* lb    = (const float*)d_in[6];
  const float* W1    = (const float*)d_in[7];
  const float* b1    = (const float*)d_in[8];
  const float* W2    = (const float*)d_in[9];
  const float* b2    = (const float*)d_in[10];
  const float* W3    = (const float*)d_in[11];
  const float* b3    = (const float*)d_in[12];

  const int Bn = in_sizes[0] / 512;            // 16384
  char* ws = (char*)d_ws;
  ushort* stateB = (ushort*)(ws + 0);          // 16384x512 bf16  (16 MB)
  ushort* W1T    = (ushort*)(ws + 16777216);   // 1024x512        (1 MB)
  ushort* W2T    = (ushort*)(ws + 17825792);   // 1024x1024       (2 MB)
  ushort* W3T    = (ushort*)(ws + 19922944);   // 32x1024 (rows>=24 zero)
  ushort* Th     = (ushort*)(ws + 19993600);   // 48x64 bf16 hi
  ushort* Tl     = (ushort*)(ws + 19999744);   // 48x64 bf16 lo
  ushort* T0h    = (ushort*)(ws + 20005888);   // 48x32 bf16 hi
  ushort* T0l    = (ushort*)(ws + 20008960);   // 48x32 bf16 lo
  float*  blp    = (float*) (ws + 20012032);   // 48
  float*  bup    = (float*) (ws + 20012224);   // 48
  ushort* H1     = (ushort*)(ws + 21565440);   // 16384x1024 bf16 (32 MB)
  ushort* H2     = (ushort*)(ws + 55119872);   // 16384x1024 bf16 (32 MB)
  float*  rawb   = (float*)d_out;              // gemm3 out = admm in (in-place)

  const int n4 = (Bn * 512) / 4;
  convert_bf16<<<(n4 + 255) / 256, 256, 0, stream>>>(state, stateB, n4);
  transpose_f32_bf16<<<dim3(32, 16), 256, 0, stream>>>(W1, W1T, 512, 1024, 1024);
  transpose_f32_bf16<<<dim3(32, 32), 256, 0, stream>>>(W2, W2T, 1024, 1024, 1024);
  transpose_f32_bf16<<<dim3(1, 32),  256, 0, stream>>>(W3, W3T, 1024, 24, 32);
  setup_admm<<<1, 256, 0, stream>>>(Aeq, beq, Ain, bin, ub, lb,
                                    Th, Tl, T0h, T0l, blp, bup);

  gemm_bt<128, 128, 2, 2, 4, 4, 0><<<dim3(8, Bn / 128), 256, 0, stream>>>(
      stateB, W1T, b1, H1, 512, 1024, 1024);
  gemm_bt<128, 128, 2, 2, 4, 4, 0><<<dim3(8, Bn / 128), 256, 0, stream>>>(
      H1, W2T, b2, H2, 1024, 1024, 1024);
  gemm_bt<64, 32, 4, 1, 1, 2, 1><<<dim3(1, Bn / 64), 256, 0, stream>>>(
      H2, W3T, b3, rawb, 1024, 24, 24);

  admm_mfma<<<Bn / 64, 256, 0, stream>>>(rawb, Th, Tl, T0h, T0l, blp, bup,
                                         (float*)d_out);
}